// Round 2
// 608.629 us; speedup vs baseline: 1.0177x; 1.0177x over previous
//
#include <hip/hip_runtime.h>
#include <cstdint>

// GridEncoder forward (torch-ngp semantics), MI355X.
// B = 1048576 points, D=3, L=16 levels, C=2, H=16, per_level_scale=2.0,
// log2_hashmap_size=19, align_corners=False.
//
// Level metadata (from the reference's _level_meta()):
//   res(l)   = 16 << l
//   scale(l) = res - 1            (exact in fp32)
//   dense levels: 0,1,2 (offsets 0, 4920, 40864), base = res+1,
//     idx = cx + cy*base + cz*base^2   (mod size is identity)
//   hashed levels: 3..15, size = 2^19 -> idx = hash & 0x7FFFF
//     offset(l) = l*524288 - 1257368
//   fast_hash primes: (1, 2654435761, 805459861)
//
// R5 == R4 resubmitted (R4 bench died to a broker-side container failure;
// kernel audited: all gathers in-bounds, 16 B loads aligned, launch is
// graph-capture safe).
//
// R4 structure:
//  * Keep R3's LEVEL-PHASED DISPATCH (level in blockIdx.y -> in-flight
//    blocks span 1-2 hash tables -> tables L2-resident; R3 counters show
//    93% L2 hit on gathers, FETCH 484 MB).
//  * R3 post-mortem: gather pass shows VALUBusy 10.7%, occupancy 86%,
//    HBM 17.6%, LDS 0 -> the limiter is diverged-request throughput
//    (~0.49 req/cy/CU). Fix: PAIRED 16 B GATHERS. For corner pair
//    (c, c+1) only x differs; when ix is even, h(c+1) = h(c)^1, so both
//    entries live in one aligned 16 B slot {h&~1, h|1} (level offsets are
//    even). One dwordx4 replaces two diverged dwordx2 for ~50% of lanes
//    -> hashed requests 8 -> 6 avg per point (-25%).
//  * Transpose pass WITHOUT LDS: R3's version spent 56 mem/LDS ops per
//    256 B (1.4 TB/s). One thread per output float4 (j = t&7, q = t>>3):
//    stores are lane-contiguous 16 B, loads per wave form 8 x 64 B
//    contiguous segments. 3 mem ops per 48 B.

namespace {

using f32x2 = __attribute__((ext_vector_type(2))) float;
using f32x4 = __attribute__((ext_vector_type(4))) float;

__device__ __forceinline__ void level_setup(
    float x, float y, float z, uint32_t l,
    uint32_t idx[8], float w[8]) {
  uint32_t res = 16u << l;
  float scale = (float)res - 1.0f;

  float px = x * scale + 0.5f;
  float py = y * scale + 0.5f;
  float pz = z * scale + 0.5f;
  float gx = floorf(px), gy = floorf(py), gz = floorf(pz);
  float rx = px - gx, ry = py - gy, rz = pz - gz;
  uint32_t ix = (uint32_t)gx, iy = (uint32_t)gy, iz = (uint32_t)gz;

  uint32_t off = (l >= 3u) ? (l * 524288u - 1257368u)
                           : ((l == 0u) ? 0u : ((l == 1u) ? 4920u : 40864u));
  bool hashed = (l >= 3u);

  uint32_t base = res + 1u;
  uint32_t bb = base * base;
  const uint32_t P2 = 2654435761u, P3 = 805459861u;

  uint32_t dy0 = iy * base, dy1 = dy0 + base;
  uint32_t dz0 = iz * bb,   dz1 = dz0 + bb;
  uint32_t hy0 = iy * P2,   hy1 = hy0 + P2;
  uint32_t hz0 = iz * P3,   hz1 = hz0 + P3;

#pragma unroll
  for (int c = 0; c < 8; ++c) {
    uint32_t cx = ix + (uint32_t)(c & 1);
    uint32_t h = (cx ^ ((c & 2) ? hy1 : hy0) ^ ((c & 4) ? hz1 : hz0)) & 0x7FFFFu;
    uint32_t d = cx + ((c & 2) ? dy1 : dy0) + ((c & 4) ? dz1 : dz0);
    idx[c] = (hashed ? h : d) + off;
  }

  float wx1 = rx, wx0 = 1.0f - rx;
  float wy1 = ry, wy0 = 1.0f - ry;
  float wz1 = rz, wz0 = 1.0f - rz;
#pragma unroll
  for (int c = 0; c < 8; ++c) {
    w[c] = ((c & 1) ? wx1 : wx0) *
           ((c & 2) ? wy1 : wy0) *
           ((c & 4) ? wz1 : wz0);
  }
}

// ---- Pass 1: level-phased gather, writes level-major ws[l*B + p] ----
__global__ __launch_bounds__(256) void gather_lm_kernel(
    const float* __restrict__ in,      // [B,3] in [-1,1]
    const f32x2* __restrict__ emb,     // [7131240] float2
    f32x2* __restrict__ ws,            // [16*B] float2, level-major
    uint32_t B) {
  uint32_t l = blockIdx.y;                       // level: slowest dispatch dim
  uint32_t p = blockIdx.x * 256u + threadIdx.x;  // point
  if (p >= B) return;

  // streaming input: nontemporal so it doesn't evict table lines in L2
  float x = (__builtin_nontemporal_load(&in[p * 3 + 0]) + 1.0f) * 0.5f;
  float y = (__builtin_nontemporal_load(&in[p * 3 + 1]) + 1.0f) * 0.5f;
  float z = (__builtin_nontemporal_load(&in[p * 3 + 2]) + 1.0f) * 0.5f;

  uint32_t res = 16u << l;
  float scale = (float)res - 1.0f;
  float px = x * scale + 0.5f;
  float py = y * scale + 0.5f;
  float pz = z * scale + 0.5f;
  float gx = floorf(px), gy = floorf(py), gz = floorf(pz);
  float rx = px - gx, ry = py - gy, rz = pz - gz;
  uint32_t ix = (uint32_t)gx, iy = (uint32_t)gy, iz = (uint32_t)gz;

  f32x2 e[8];

  if (l >= 3u) {
    // ---- hashed level: paired 16 B gathers where the hash allows ----
    uint32_t off = l * 524288u - 1257368u;          // even
    const f32x2* __restrict__ tab = emb + off;
    const uint32_t P2 = 2654435761u, P3 = 805459861u;
    uint32_t hy0 = iy * P2, hy1 = hy0 + P2;
    uint32_t hz0 = iz * P3, hz1 = hz0 + P3;
    // hb[j]: j bit0 = y-corner, bit1 = z-corner (matches c>>1)
    uint32_t hb0 = hy0 ^ hz0, hb1 = hy1 ^ hz0, hb2 = hy0 ^ hz1, hb3 = hy1 ^ hz1;
    uint32_t hb[4] = {hb0, hb1, hb2, hb3};

    if ((ix & 1u) == 0u) {
      // ix even: h(c+1) = h(c)^1 -> both corners live in the aligned
      // 16 B pair {h&~1, h|1}. 4 dwordx4 loads instead of 8 dwordx2.
#pragma unroll
      for (int j = 0; j < 4; ++j) {
        uint32_t h0 = (ix ^ hb[j]) & 0x7FFFFu;
        f32x4 v = *reinterpret_cast<const f32x4*>(tab + (h0 & ~1u));
        f32x2 lo; lo.x = v.x; lo.y = v.y;
        f32x2 hi; hi.x = v.z; hi.y = v.w;
        bool swap = (h0 & 1u) != 0u;
        e[2 * j]     = swap ? hi : lo;
        e[2 * j + 1] = swap ? lo : hi;
      }
    } else {
      uint32_t ix1 = ix + 1u;
#pragma unroll
      for (int j = 0; j < 4; ++j) {
        e[2 * j]     = tab[(ix  ^ hb[j]) & 0x7FFFFu];
        e[2 * j + 1] = tab[(ix1 ^ hb[j]) & 0x7FFFFu];
      }
    }
  } else {
    // ---- dense level ----
    uint32_t off = (l == 0u) ? 0u : ((l == 1u) ? 4920u : 40864u);
    uint32_t base = res + 1u;
    uint32_t bb = base * base;
    uint32_t dy0 = iy * base, dy1 = dy0 + base;
    uint32_t dz0 = iz * bb,   dz1 = dz0 + bb;
#pragma unroll
    for (int c = 0; c < 8; ++c) {
      uint32_t cx = ix + (uint32_t)(c & 1);
      uint32_t d = cx + ((c & 2) ? dy1 : dy0) + ((c & 4) ? dz1 : dz0);
      e[c] = emb[d + off];
    }
  }

  float wx1 = rx, wx0 = 1.0f - rx;
  float wy1 = ry, wy0 = 1.0f - ry;
  float wz1 = rz, wz0 = 1.0f - rz;

  float o0 = 0.0f, o1 = 0.0f;
#pragma unroll
  for (int c = 0; c < 8; ++c) {
    float w = ((c & 1) ? wx1 : wx0) *
              ((c & 2) ? wy1 : wy0) *
              ((c & 4) ? wz1 : wz0);
    o0 = fmaf(w, e[c].x, o0);
    o1 = fmaf(w, e[c].y, o1);
  }

  f32x2 r; r.x = o0; r.y = o1;
  __builtin_nontemporal_store(r, &ws[(size_t)l * B + p]);  // coalesced 8 B/lane
}

// ---- Pass 2: transpose level-major ws -> point-major out, no LDS ----
// One thread per output float4 (= levels 2j, 2j+1 of point q).
// t = q*8 + j; stores are lane-contiguous 16 B; loads per wave instruction
// form 8 contiguous 64 B segments (one per j-group of 8 lanes).
__global__ __launch_bounds__(256) void transpose_kernel(
    const f32x2* __restrict__ ws,   // [16*B] level-major
    f32x4* __restrict__ out,        // [B*8] float4 == [B,16,2] floats
    uint32_t B) {
  uint32_t t = blockIdx.x * 256u + threadIdx.x;
  if (t >= B * 8u) return;
  uint32_t j = t & 7u;
  uint32_t q = t >> 3;
  f32x2 a = __builtin_nontemporal_load(&ws[(size_t)(2u * j)      * B + q]);
  f32x2 b = __builtin_nontemporal_load(&ws[(size_t)(2u * j + 1u) * B + q]);
  f32x4 v; v.x = a.x; v.y = a.y; v.z = b.x; v.w = b.y;
  __builtin_nontemporal_store(v, &out[t]);
}

// ---- Fallback (ws too small): single-pass kernel ----
__global__ __launch_bounds__(256) void grid_encode_fallback(
    const float* __restrict__ in, const f32x2* __restrict__ emb,
    f32x4* __restrict__ out, uint32_t B) {
  uint32_t p = blockIdx.x * 256u + threadIdx.x;
  if (p >= B) return;
  float x = (in[p * 3 + 0] + 1.0f) * 0.5f;
  float y = (in[p * 3 + 1] + 1.0f) * 0.5f;
  float z = (in[p * 3 + 2] + 1.0f) * 0.5f;
#pragma unroll 1
  for (uint32_t l = 0; l < 16u; l += 2u) {
    uint32_t ia[8], ib[8]; float wa[8], wb[8];
    level_setup(x, y, z, l, ia, wa);
    level_setup(x, y, z, l + 1u, ib, wb);
    f32x2 ea[8], eb[8];
#pragma unroll
    for (int c = 0; c < 8; ++c) ea[c] = emb[ia[c]];
#pragma unroll
    for (int c = 0; c < 8; ++c) eb[c] = emb[ib[c]];
    float a0 = 0, a1 = 0, b0 = 0, b1 = 0;
#pragma unroll
    for (int c = 0; c < 8; ++c) {
      a0 = fmaf(wa[c], ea[c].x, a0);
      a1 = fmaf(wa[c], ea[c].y, a1);
      b0 = fmaf(wb[c], eb[c].x, b0);
      b1 = fmaf(wb[c], eb[c].y, b1);
    }
    f32x4 v; v.x = a0; v.y = a1; v.z = b0; v.w = b1;
    out[(size_t)p * 8u + (l >> 1)] = v;
  }
}

}  // namespace

extern "C" void kernel_launch(void* const* d_in, const int* in_sizes, int n_in,
                              void* d_out, int out_size, void* d_ws, size_t ws_size,
                              hipStream_t stream) {
  (void)n_in; (void)out_size;
  const float* in = (const float*)d_in[0];
  const f32x2* emb = (const f32x2*)d_in[1];
  f32x4* out = (f32x4*)d_out;
  uint32_t B = (uint32_t)(in_sizes[0] / 3);
  uint32_t pblocks = (B + 255u) / 256u;

  size_t ws_needed = (size_t)16 * B * sizeof(f32x2);   // 128 MiB at B=1M
  if (ws_size >= ws_needed) {
    f32x2* ws = (f32x2*)d_ws;
    hipLaunchKernelGGL(gather_lm_kernel, dim3(pblocks, 16), dim3(256), 0,
                       stream, in, emb, ws, B);
    uint32_t tblocks = (B * 8u + 255u) / 256u;
    hipLaunchKernelGGL(transpose_kernel, dim3(tblocks), dim3(256), 0,
                       stream, ws, out, B);
  } else {
    hipLaunchKernelGGL(grid_encode_fallback, dim3(pblocks), dim3(256), 0,
                       stream, in, emb, out, B);
  }
}